// Round 3
// baseline (198.233 us; speedup 1.0000x reference)
//
#include <hip/hip_runtime.h>
#include <hip/hip_bf16.h>
#include <math.h>

#define GRIDN 1024
#define NAGENTS 262144
#define CCH 8
#define HIDDEN 64
#define DT 0.1f
#define DECAYF 0.99f
#define SENSOR_LEN 3.0f
// cos(0.6), sin(0.6)
#define COS_SA 0.82533561490967829724f
#define SIN_SA 0.56464247339503535720f

typedef __attribute__((ext_vector_type(8))) short short8;

// tanh(x) = (2^(2x*log2e) - 1) / (2^(2x*log2e) + 1), clamped so exp2 can't overflow
__device__ __forceinline__ float fast_tanh(float x) {
    float xc = fminf(fmaxf(x, -9.0f), 9.0f);
    float t = __builtin_amdgcn_exp2f(xc * 2.88539008177792681472f);  // 2*log2(e)
    return (t - 1.0f) * __builtin_amdgcn_rcpf(t + 1.0f);
}

__device__ __forceinline__ float bf16_lo(unsigned u) {
    return __builtin_bit_cast(float, u << 16);
}
__device__ __forceinline__ float bf16_hi(unsigned u) {
    return __builtin_bit_cast(float, u & 0xffff0000u);
}

// BT[x][y][c] = 3x3 torus box sum of lattice channel c at (x,y), stored bf16.
// Also initializes winner[idx] = -1 (fused to save a dispatch).
__global__ void __launch_bounds__(256) k_boxT(const float* __restrict__ lat,
                                              __hip_bfloat16* __restrict__ BT,
                                              int* __restrict__ winner) {
    int idx = blockIdx.x * blockDim.x + threadIdx.x;  // 0 .. 1M-1
    winner[idx] = -1;
    int x = idx >> 10, y = idx & (GRIDN - 1);
    int xm = (x + GRIDN - 1) & (GRIDN - 1), xp = (x + 1) & (GRIDN - 1);
    int ym = (y + GRIDN - 1) & (GRIDN - 1), yp = (y + 1) & (GRIDN - 1);
    __hip_bfloat16 out[CCH];
#pragma unroll
    for (int c = 0; c < CCH; ++c) {
        const float* L = lat + (size_t)c * GRIDN * GRIDN;
        const float* r0 = L + xm * GRIDN;
        const float* r1 = L + x * GRIDN;
        const float* r2 = L + xp * GRIDN;
        float s = r0[ym] + r0[y] + r0[yp]
                + r1[ym] + r1[y] + r1[yp]
                + r2[ym] + r2[y] + r2[yp];
        out[c] = __float2bfloat16(s);
    }
    *(short8*)(BT + (size_t)idx * CCH) = *(const short8*)out;
}

// 4 threads per agent; thread t owns hidden slice [t*16, t*16+16).
// t in {0,1,2}: gathers sensor t; t==3 duplicates sensor 0 (same cache line).
// Layer-2 partials reduced across the quad; divergent tails split output work.
__global__ void __launch_bounds__(256) k_agent(
    const float* __restrict__ pos, const float* __restrict__ vel,
    const __hip_bfloat16* __restrict__ BT,
    const float* __restrict__ W1, const float* __restrict__ b1,
    const float* __restrict__ W2, const float* __restrict__ b2,
    float* __restrict__ out_pos, float* __restrict__ out_vel,
    float* __restrict__ dp, int* __restrict__ winner) {
    int tid = blockIdx.x * blockDim.x + threadIdx.x;
    int i = tid >> 2;        // agent
    int t = tid & 3;         // quad lane

    float px = pos[i], py = pos[i + NAGENTS];
    float vx = vel[i], vy = vel[i + NAGENTS];

    float r2 = vx * vx + vy * vy;
    float ct, st;
    if (r2 > 0.f) {
        float inv = rsqrtf(r2);
        ct = vx * inv;
        st = vy * inv;
    } else {
        ct = 1.f;  // atan2(0,0) = 0
        st = 0.f;
    }

    // my sensor direction: t==0/3 front, t==1 left(+0.6), t==2 right(-0.6)
    float dx, dy;
    if (t == 1)      { dx = ct * COS_SA - st * SIN_SA; dy = st * COS_SA + ct * SIN_SA; }
    else if (t == 2) { dx = ct * COS_SA + st * SIN_SA; dy = st * COS_SA - ct * SIN_SA; }
    else             { dx = ct;                        dy = st; }

    int gx = ((int)rintf(px + SENSOR_LEN * dx) + GRIDN) & (GRIDN - 1);
    int gy = ((int)rintf(py + SENSOR_LEN * dy) + GRIDN) & (GRIDN - 1);
    uint4 u = *(const uint4*)(BT + ((size_t)(gx << 10) + gy) * CCH);

    // broadcast all 3 sensors' packed bf16 across the quad: xk[s*4+d]
    unsigned xk[12];
#pragma unroll
    for (int s = 0; s < 3; ++s) {
        xk[s * 4 + 0] = __shfl(u.x, s, 4);
        xk[s * 4 + 1] = __shfl(u.y, s, 4);
        xk[s * 4 + 2] = __shfl(u.z, s, 4);
        xk[s * 4 + 3] = __shfl(u.w, s, 4);
    }

    // layer 1: h[jj] = b1[j] + sum_k x[k]*W1[k][j], j = t*16+jj
    float h[16];
    const float4* b1v = (const float4*)(b1 + t * 16);
#pragma unroll
    for (int q = 0; q < 4; ++q) {
        float4 b = b1v[q];
        h[q * 4 + 0] = b.x; h[q * 4 + 1] = b.y;
        h[q * 4 + 2] = b.z; h[q * 4 + 3] = b.w;
    }
#pragma unroll
    for (int k = 0; k < 3 * CCH; ++k) {
        float xv = (k & 1) ? bf16_hi(xk[k >> 1]) : bf16_lo(xk[k >> 1]);
        const float4* wr = (const float4*)(W1 + k * HIDDEN + t * 16);
#pragma unroll
        for (int q = 0; q < 4; ++q) {
            float4 w = wr[q];
            h[q * 4 + 0] = fmaf(xv, w.x, h[q * 4 + 0]);
            h[q * 4 + 1] = fmaf(xv, w.y, h[q * 4 + 1]);
            h[q * 4 + 2] = fmaf(xv, w.z, h[q * 4 + 2]);
            h[q * 4 + 3] = fmaf(xv, w.w, h[q * 4 + 3]);
        }
    }

    // layer 2 partial over my 16 hidden units
    float o[2 + CCH];
#pragma unroll
    for (int k = 0; k < 2 + CCH; ++k) o[k] = 0.f;
#pragma unroll
    for (int jj = 0; jj < 16; ++jj) {
        float tj = fast_tanh(h[jj]);
        const float* w2 = W2 + (t * 16 + jj) * (2 + CCH);
#pragma unroll
        for (int k = 0; k < 2 + CCH; ++k) o[k] = fmaf(tj, w2[k], o[k]);
    }

    // quad butterfly reduce, then bias (every lane ends with full o)
#pragma unroll
    for (int k = 0; k < 2 + CCH; ++k) {
        o[k] += __shfl_xor(o[k], 1, 4);
        o[k] += __shfl_xor(o[k], 2, 4);
        o[k] += b2[k];
    }

    if (t == 0) {
        float nvx = o[0], nvy = o[1];
        // pos in [2,1022], |vel*DT| tiny -> at most one wrap either side
        float npx = px + nvx * DT;
        if (npx >= (float)GRIDN) npx -= (float)GRIDN;
        if (npx < 0.f) npx += (float)GRIDN;
        float npy = py + nvy * DT;
        if (npy >= (float)GRIDN) npy -= (float)GRIDN;
        if (npy < 0.f) npy += (float)GRIDN;
        out_pos[i] = npx;
        out_pos[i + NAGENTS] = npy;
        out_vel[i] = nvx;
        out_vel[i + NAGENTS] = nvy;
    } else if (t == 1) {
        *(float4*)(dp + (size_t)i * CCH) = make_float4(o[2], o[3], o[4], o[5]);
    } else if (t == 2) {
        *(float4*)(dp + (size_t)i * CCH + 4) = make_float4(o[6], o[7], o[8], o[9]);
    } else {
        int wx = (int)rintf(px) & (GRIDN - 1);
        int wy = (int)rintf(py) & (GRIDN - 1);
        atomicMax(&winner[(wx << 10) + wy], i);
    }
}

__global__ void __launch_bounds__(256) k_update(const float* __restrict__ lat,
                                                const int* __restrict__ winner,
                                                const float* __restrict__ dp,
                                                float* __restrict__ out_lat) {
    int idx = blockIdx.x * blockDim.x + threadIdx.x;  // cell index
    int w = winner[idx];
    float d[CCH];
    if (w >= 0) {
        const float4* dpp = (const float4*)(dp + (size_t)w * CCH);
        float4 a = dpp[0], b = dpp[1];
        d[0] = a.x; d[1] = a.y; d[2] = a.z; d[3] = a.w;
        d[4] = b.x; d[5] = b.y; d[6] = b.z; d[7] = b.w;
    }
#pragma unroll
    for (int c = 0; c < CCH; ++c) {
        size_t off = (size_t)c * GRIDN * GRIDN + idx;
        float v = lat[off];
        if (w >= 0) v = fmaxf(v + DT * d[c], 0.f);
        out_lat[off] = v * DECAYF;
    }
}

extern "C" void kernel_launch(void* const* d_in, const int* in_sizes, int n_in,
                              void* d_out, int out_size, void* d_ws, size_t ws_size,
                              hipStream_t stream) {
    const float* pos = (const float*)d_in[0];
    const float* vel = (const float*)d_in[1];
    const float* lat = (const float*)d_in[2];
    const float* W1  = (const float*)d_in[3];
    const float* b1  = (const float*)d_in[4];
    const float* W2  = (const float*)d_in[5];
    const float* b2  = (const float*)d_in[6];

    float* out      = (float*)d_out;
    float* out_pos  = out;                 // (2, N)
    float* out_vel  = out + 2 * NAGENTS;   // (2, N)
    float* out_lat  = out + 4 * NAGENTS;   // (C, G, G)

    char* ws = (char*)d_ws;
    int*            winner = (int*)ws;                           // 4 MB
    float*          dp     = (float*)(ws + (4 << 20));           // 8 MB
    __hip_bfloat16* BT     = (__hip_bfloat16*)(ws + (12 << 20)); // 16 MB

    const int ncell = GRIDN * GRIDN;

    k_boxT<<<ncell / 256, 256, 0, stream>>>(lat, BT, winner);
    k_agent<<<NAGENTS * 4 / 256, 256, 0, stream>>>(pos, vel, BT, W1, b1, W2, b2,
                                                   out_pos, out_vel, dp, winner);
    k_update<<<ncell / 256, 256, 0, stream>>>(lat, winner, dp, out_lat);
}

// Round 4
// 62.067 us; speedup vs baseline: 3.1939x; 3.1939x over previous
//
#include <hip/hip_runtime.h>
#include <hip/hip_bf16.h>
#include <math.h>

#define GRIDN 1024
#define NAGENTS 262144
#define CCH 8
#define HIDDEN 64
#define DT 0.1f
#define DECAYF 0.99f
#define SENSOR_LEN 3.0f
// cos(0.6), sin(0.6)
#define COS_SA 0.82533561490967829724f
#define SIN_SA 0.56464247339503535720f

typedef __attribute__((ext_vector_type(8))) short short8;

// tanh(x) = (2^(2x*log2e) - 1) / (2^(2x*log2e) + 1), clamped so exp2 can't overflow
__device__ __forceinline__ float fast_tanh(float x) {
    float xc = fminf(fmaxf(x, -9.0f), 9.0f);
    float t = __builtin_amdgcn_exp2f(xc * 2.88539008177792681472f);  // 2*log2(e)
    return (t - 1.0f) * __builtin_amdgcn_rcpf(t + 1.0f);
}

__device__ __forceinline__ float bf16_lo(unsigned u) {
    return __builtin_bit_cast(float, u << 16);
}
__device__ __forceinline__ float bf16_hi(unsigned u) {
    return __builtin_bit_cast(float, u & 0xffff0000u);
}

// BT[x][y][c] = 3x3 torus box sum of lattice channel c at (x,y), stored bf16.
// Also initializes winner[idx] = -1 (fused to save a dispatch).
__global__ void __launch_bounds__(256) k_boxT(const float* __restrict__ lat,
                                              __hip_bfloat16* __restrict__ BT,
                                              int* __restrict__ winner) {
    int idx = blockIdx.x * blockDim.x + threadIdx.x;  // 0 .. 1M-1
    winner[idx] = -1;
    int x = idx >> 10, y = idx & (GRIDN - 1);
    int xm = (x + GRIDN - 1) & (GRIDN - 1), xp = (x + 1) & (GRIDN - 1);
    int ym = (y + GRIDN - 1) & (GRIDN - 1), yp = (y + 1) & (GRIDN - 1);
    __hip_bfloat16 out[CCH];
#pragma unroll
    for (int c = 0; c < CCH; ++c) {
        const float* L = lat + (size_t)c * GRIDN * GRIDN;
        const float* r0 = L + xm * GRIDN;
        const float* r1 = L + x * GRIDN;
        const float* r2 = L + xp * GRIDN;
        float s = r0[ym] + r0[y] + r0[yp]
                + r1[ym] + r1[y] + r1[yp]
                + r2[ym] + r2[y] + r2[yp];
        out[c] = __float2bfloat16(s);
    }
    *(short8*)(BT + (size_t)idx * CCH) = *(const short8*)out;
}

// Block = 256 threads = 4 waves; block handles 64 agents (agent = base + lane).
// Wave w computes hidden slice [w*16, w*16+16) for all 64 agents.
// KEY: slice index is pinned to an SGPR via readfirstlane so ALL weight
// addresses stay wave-uniform -> s_load into SGPRs (round-3 regression was
// lane-varying weight addresses turning these into 100M vector loads).
__global__ void __launch_bounds__(256) k_agent(
    const float* __restrict__ pos, const float* __restrict__ vel,
    const __hip_bfloat16* __restrict__ BT,
    const float* __restrict__ W1, const float* __restrict__ b1,
    const float* __restrict__ W2, const float* __restrict__ b2,
    float* __restrict__ out_pos, float* __restrict__ out_vel,
    float* __restrict__ dp, int* __restrict__ winner) {
    __shared__ float part[4][64][13];  // 13-pad: stride coprime with 32 banks

    int lane = threadIdx.x & 63;
    int wq = __builtin_amdgcn_readfirstlane(threadIdx.x >> 6);  // SGPR slice id
    int i = blockIdx.x * 64 + lane;  // agent

    float px = pos[i], py = pos[i + NAGENTS];
    float vx = vel[i], vy = vel[i + NAGENTS];

    float r2 = vx * vx + vy * vy;
    float ct, st;
    if (r2 > 0.f) {
        float inv = rsqrtf(r2);
        ct = vx * inv;
        st = vy * inv;
    } else {
        ct = 1.f;  // atan2(0,0) = 0
        st = 0.f;
    }

    // sensor directions: front, +0.6 (left), -0.6 (right)
    float dirx[3], diry[3];
    dirx[0] = ct;                          diry[0] = st;
    dirx[1] = ct * COS_SA - st * SIN_SA;   diry[1] = st * COS_SA + ct * SIN_SA;
    dirx[2] = ct * COS_SA + st * SIN_SA;   diry[2] = st * COS_SA - ct * SIN_SA;

    uint4 raw[3];
#pragma unroll
    for (int s = 0; s < 3; ++s) {
        int gx = ((int)rintf(px + SENSOR_LEN * dirx[s]) + GRIDN) & (GRIDN - 1);
        int gy = ((int)rintf(py + SENSOR_LEN * diry[s]) + GRIDN) & (GRIDN - 1);
        raw[s] = *(const uint4*)(BT + ((size_t)(gx << 10) + gy) * CCH);
    }
    unsigned xk[12];
#pragma unroll
    for (int s = 0; s < 3; ++s) {
        xk[s * 4 + 0] = raw[s].x; xk[s * 4 + 1] = raw[s].y;
        xk[s * 4 + 2] = raw[s].z; xk[s * 4 + 3] = raw[s].w;
    }

    // layer 1: h[jj] = b1[wq*16+jj] + sum_k x[k]*W1[k][wq*16+jj]
    float h[16];
    {
        const float4* b1v = (const float4*)(b1 + wq * 16);
#pragma unroll
        for (int q = 0; q < 4; ++q) {
            float4 b = b1v[q];
            h[q * 4 + 0] = b.x; h[q * 4 + 1] = b.y;
            h[q * 4 + 2] = b.z; h[q * 4 + 3] = b.w;
        }
    }
#pragma unroll
    for (int k = 0; k < 3 * CCH; ++k) {
        float xv = (k & 1) ? bf16_hi(xk[k >> 1]) : bf16_lo(xk[k >> 1]);
        const float4* wr = (const float4*)(W1 + k * HIDDEN + wq * 16);
#pragma unroll
        for (int q = 0; q < 4; ++q) {
            float4 w = wr[q];
            h[q * 4 + 0] = fmaf(xv, w.x, h[q * 4 + 0]);
            h[q * 4 + 1] = fmaf(xv, w.y, h[q * 4 + 1]);
            h[q * 4 + 2] = fmaf(xv, w.z, h[q * 4 + 2]);
            h[q * 4 + 3] = fmaf(xv, w.w, h[q * 4 + 3]);
        }
    }

    // layer 2 partial over my 16 hidden units (bias added after reduce)
    float o[2 + CCH];
#pragma unroll
    for (int k = 0; k < 2 + CCH; ++k) o[k] = 0.f;
#pragma unroll
    for (int jj = 0; jj < 16; ++jj) {
        float tj = fast_tanh(h[jj]);
        const float* w2 = W2 + (wq * 16 + jj) * (2 + CCH);
#pragma unroll
        for (int k = 0; k < 2 + CCH; ++k) o[k] = fmaf(tj, w2[k], o[k]);
    }

#pragma unroll
    for (int k = 0; k < 2 + CCH; ++k) part[wq][lane][k] = o[k];
    __syncthreads();

    // epilogue duties split by wave
    if (wq == 0) {
        float s0 = part[0][lane][0] + part[1][lane][0] + part[2][lane][0] + part[3][lane][0] + b2[0];
        float s1 = part[0][lane][1] + part[1][lane][1] + part[2][lane][1] + part[3][lane][1] + b2[1];
        float npx = px + s0 * DT;
        if (npx >= (float)GRIDN) npx -= (float)GRIDN;
        if (npx < 0.f) npx += (float)GRIDN;
        float npy = py + s1 * DT;
        if (npy >= (float)GRIDN) npy -= (float)GRIDN;
        if (npy < 0.f) npy += (float)GRIDN;
        out_pos[i] = npx;
        out_pos[i + NAGENTS] = npy;
        out_vel[i] = s0;
        out_vel[i + NAGENTS] = s1;
    } else if (wq == 1) {
        float d0 = part[0][lane][2] + part[1][lane][2] + part[2][lane][2] + part[3][lane][2] + b2[2];
        float d1 = part[0][lane][3] + part[1][lane][3] + part[2][lane][3] + part[3][lane][3] + b2[3];
        float d2 = part[0][lane][4] + part[1][lane][4] + part[2][lane][4] + part[3][lane][4] + b2[4];
        float d3 = part[0][lane][5] + part[1][lane][5] + part[2][lane][5] + part[3][lane][5] + b2[5];
        *(float4*)(dp + (size_t)i * CCH) = make_float4(d0, d1, d2, d3);
    } else if (wq == 2) {
        float d4 = part[0][lane][6] + part[1][lane][6] + part[2][lane][6] + part[3][lane][6] + b2[6];
        float d5 = part[0][lane][7] + part[1][lane][7] + part[2][lane][7] + part[3][lane][7] + b2[7];
        float d6 = part[0][lane][8] + part[1][lane][8] + part[2][lane][8] + part[3][lane][8] + b2[8];
        float d7 = part[0][lane][9] + part[1][lane][9] + part[2][lane][9] + part[3][lane][9] + b2[9];
        *(float4*)(dp + (size_t)i * CCH + 4) = make_float4(d4, d5, d6, d7);
    } else {
        int wx = (int)rintf(px) & (GRIDN - 1);
        int wy = (int)rintf(py) & (GRIDN - 1);
        atomicMax(&winner[(wx << 10) + wy], i);
    }
}

__global__ void __launch_bounds__(256) k_update(const float* __restrict__ lat,
                                                const int* __restrict__ winner,
                                                const float* __restrict__ dp,
                                                float* __restrict__ out_lat) {
    int idx = blockIdx.x * blockDim.x + threadIdx.x;  // cell index
    int w = winner[idx];
    float d[CCH];
    if (w >= 0) {
        const float4* dpp = (const float4*)(dp + (size_t)w * CCH);
        float4 a = dpp[0], b = dpp[1];
        d[0] = a.x; d[1] = a.y; d[2] = a.z; d[3] = a.w;
        d[4] = b.x; d[5] = b.y; d[6] = b.z; d[7] = b.w;
    }
#pragma unroll
    for (int c = 0; c < CCH; ++c) {
        size_t off = (size_t)c * GRIDN * GRIDN + idx;
        float v = lat[off];
        if (w >= 0) v = fmaxf(v + DT * d[c], 0.f);
        out_lat[off] = v * DECAYF;
    }
}

extern "C" void kernel_launch(void* const* d_in, const int* in_sizes, int n_in,
                              void* d_out, int out_size, void* d_ws, size_t ws_size,
                              hipStream_t stream) {
    const float* pos = (const float*)d_in[0];
    const float* vel = (const float*)d_in[1];
    const float* lat = (const float*)d_in[2];
    const float* W1  = (const float*)d_in[3];
    const float* b1  = (const float*)d_in[4];
    const float* W2  = (const float*)d_in[5];
    const float* b2  = (const float*)d_in[6];

    float* out      = (float*)d_out;
    float* out_pos  = out;                 // (2, N)
    float* out_vel  = out + 2 * NAGENTS;   // (2, N)
    float* out_lat  = out + 4 * NAGENTS;   // (C, G, G)

    char* ws = (char*)d_ws;
    int*            winner = (int*)ws;                           // 4 MB
    float*          dp     = (float*)(ws + (4 << 20));           // 8 MB
    __hip_bfloat16* BT     = (__hip_bfloat16*)(ws + (12 << 20)); // 16 MB

    const int ncell = GRIDN * GRIDN;

    k_boxT<<<ncell / 256, 256, 0, stream>>>(lat, BT, winner);
    k_agent<<<NAGENTS / 64, 256, 0, stream>>>(pos, vel, BT, W1, b1, W2, b2,
                                              out_pos, out_vel, dp, winner);
    k_update<<<ncell / 256, 256, 0, stream>>>(lat, winner, dp, out_lat);
}

// Round 5
// 60.592 us; speedup vs baseline: 3.2716x; 1.0243x over previous
//
#include <hip/hip_runtime.h>
#include <hip/hip_bf16.h>
#include <math.h>

#define GRIDN 1024
#define NAGENTS 262144
#define CCH 8
#define HIDDEN 64
#define DT 0.1f
#define DECAYF 0.99f
#define SENSOR_LEN 3.0f
// cos(0.6), sin(0.6)
#define COS_SA 0.82533561490967829724f
#define SIN_SA 0.56464247339503535720f

typedef __attribute__((ext_vector_type(8))) short short8;
typedef __attribute__((ext_vector_type(2))) _Float16 half2v;

// packed 2-way f16 dot with f32 accumulate: v_dot2_f32_f16
__device__ __forceinline__ float dot2f(unsigned a, unsigned b, float c) {
#if __has_builtin(__builtin_amdgcn_fdot2)
    return __builtin_amdgcn_fdot2(__builtin_bit_cast(half2v, a),
                                  __builtin_bit_cast(half2v, b), c, false);
#else
    half2v ha = __builtin_bit_cast(half2v, a), hb = __builtin_bit_cast(half2v, b);
    return c + (float)ha.x * (float)hb.x + (float)ha.y * (float)hb.y;
#endif
}

__device__ __forceinline__ unsigned packh(float a, float b) {
    _Float16 ha = (_Float16)a, hb = (_Float16)b;
    unsigned short ua = __builtin_bit_cast(unsigned short, ha);
    unsigned short ub = __builtin_bit_cast(unsigned short, hb);
    return (unsigned)ua | ((unsigned)ub << 16);
}

// tanh(x) = (2^(2x*log2e) - 1) / (2^(2x*log2e) + 1), clamped so exp2 can't overflow
__device__ __forceinline__ float fast_tanh(float x) {
    float xc = fminf(fmaxf(x, -9.0f), 9.0f);
    float t = __builtin_amdgcn_exp2f(xc * 2.88539008177792681472f);  // 2*log2(e)
    return (t - 1.0f) * __builtin_amdgcn_rcpf(t + 1.0f);
}

// BT[x][y][c] = 3x3 torus box sum of lattice channel c at (x,y), stored f16.
// Fused: winner init; block 0 also pre-pairs W1/W2 into f16x2 words for dot2.
// W1p[p*64+j]   = (f16(W1[2p][j]),   f16(W1[2p+1][j]))    p=0..11
// W2p[pg*16+k]  = (f16(W2[2pg][k]),  f16(W2[2pg+1][k]))   pg=0..31, k<10 (pad 16)
__global__ void __launch_bounds__(256) k_boxT(const float* __restrict__ lat,
                                              _Float16* __restrict__ BT,
                                              int* __restrict__ winner,
                                              const float* __restrict__ W1,
                                              const float* __restrict__ W2,
                                              unsigned* __restrict__ W1p,
                                              unsigned* __restrict__ W2p) {
    if (blockIdx.x == 0) {
        for (int t = threadIdx.x; t < 768 + 512; t += 256) {
            if (t < 768) {
                int p = t >> 6, j = t & 63;
                W1p[t] = packh(W1[(2 * p) * HIDDEN + j], W1[(2 * p + 1) * HIDDEN + j]);
            } else {
                int q = t - 768;
                int pg = q >> 4, k = q & 15;
                unsigned v = 0;
                if (k < 10) v = packh(W2[(2 * pg) * 10 + k], W2[(2 * pg + 1) * 10 + k]);
                W2p[q] = v;
            }
        }
    }
    int idx = blockIdx.x * blockDim.x + threadIdx.x;  // 0 .. 1M-1
    winner[idx] = -1;
    int x = idx >> 10, y = idx & (GRIDN - 1);
    int xm = (x + GRIDN - 1) & (GRIDN - 1), xp = (x + 1) & (GRIDN - 1);
    int ym = (y + GRIDN - 1) & (GRIDN - 1), yp = (y + 1) & (GRIDN - 1);
    _Float16 out[CCH];
#pragma unroll
    for (int c = 0; c < CCH; ++c) {
        const float* L = lat + (size_t)c * GRIDN * GRIDN;
        const float* r0 = L + xm * GRIDN;
        const float* r1 = L + x * GRIDN;
        const float* r2 = L + xp * GRIDN;
        float s = r0[ym] + r0[y] + r0[yp]
                + r1[ym] + r1[y] + r1[yp]
                + r2[ym] + r2[y] + r2[yp];
        out[c] = (_Float16)s;
    }
    *(short8*)(BT + (size_t)idx * CCH) = *(const short8*)out;
}

// Block = 256 threads = 4 waves; block handles 64 agents (agent = base + lane).
// Wave w computes hidden slice [w*16, w*16+16) for all 64 agents; slice id is
// pinned to SGPR (readfirstlane) so weight addresses stay wave-uniform (s_load).
// MLP math uses v_dot2_f32_f16: gathered u32 is directly a (c,c+1) f16 pair.
__global__ void __launch_bounds__(256) k_agent(
    const float* __restrict__ pos, const float* __restrict__ vel,
    const _Float16* __restrict__ BT,
    const unsigned* __restrict__ W1p, const float* __restrict__ b1,
    const unsigned* __restrict__ W2p, const float* __restrict__ b2,
    float* __restrict__ out_pos, float* __restrict__ out_vel,
    float* __restrict__ dp, int* __restrict__ winner) {
    __shared__ float part[4][64][13];  // 13-pad: stride coprime with 32 banks

    int lane = threadIdx.x & 63;
    int wq = __builtin_amdgcn_readfirstlane(threadIdx.x >> 6);  // SGPR slice id
    int i = blockIdx.x * 64 + lane;  // agent

    float px = pos[i], py = pos[i + NAGENTS];
    float vx = vel[i], vy = vel[i + NAGENTS];

    float r2 = vx * vx + vy * vy;
    float ct, st;
    if (r2 > 0.f) {
        float inv = rsqrtf(r2);
        ct = vx * inv;
        st = vy * inv;
    } else {
        ct = 1.f;  // atan2(0,0) = 0
        st = 0.f;
    }

    // sensor directions: front, +0.6 (left), -0.6 (right)
    float dirx[3], diry[3];
    dirx[0] = ct;                          diry[0] = st;
    dirx[1] = ct * COS_SA - st * SIN_SA;   diry[1] = st * COS_SA + ct * SIN_SA;
    dirx[2] = ct * COS_SA + st * SIN_SA;   diry[2] = st * COS_SA - ct * SIN_SA;

    uint4 raw[3];
#pragma unroll
    for (int s = 0; s < 3; ++s) {
        int gx = ((int)rintf(px + SENSOR_LEN * dirx[s]) + GRIDN) & (GRIDN - 1);
        int gy = ((int)rintf(py + SENSOR_LEN * diry[s]) + GRIDN) & (GRIDN - 1);
        raw[s] = *(const uint4*)(BT + ((size_t)(gx << 10) + gy) * CCH);
    }
    // xk[p] = f16 pair (x[2p], x[2p+1]), p = 0..11  (x = [front8, left8, right8])
    unsigned xk[12];
#pragma unroll
    for (int s = 0; s < 3; ++s) {
        xk[s * 4 + 0] = raw[s].x; xk[s * 4 + 1] = raw[s].y;
        xk[s * 4 + 2] = raw[s].z; xk[s * 4 + 3] = raw[s].w;
    }

    // layer 1: h[jj] = b1[wq*16+jj] + sum_p dot2(x_pair[p], W1pair[p][wq*16+jj])
    float h[16];
    {
        const float4* b1v = (const float4*)(b1 + wq * 16);
#pragma unroll
        for (int q = 0; q < 4; ++q) {
            float4 b = b1v[q];
            h[q * 4 + 0] = b.x; h[q * 4 + 1] = b.y;
            h[q * 4 + 2] = b.z; h[q * 4 + 3] = b.w;
        }
    }
#pragma unroll
    for (int p = 0; p < 12; ++p) {
        unsigned xp = xk[p];
        const unsigned* wrow = W1p + p * HIDDEN + wq * 16;  // wave-uniform
#pragma unroll
        for (int jj = 0; jj < 16; ++jj) h[jj] = dot2f(xp, wrow[jj], h[jj]);
    }

    // layer 2 partial: tanh, pack to f16 pairs, dot2 against pre-paired W2
    unsigned hp[8];
#pragma unroll
    for (int p = 0; p < 8; ++p)
        hp[p] = packh(fast_tanh(h[2 * p]), fast_tanh(h[2 * p + 1]));

    float o[2 + CCH];
#pragma unroll
    for (int k = 0; k < 2 + CCH; ++k) o[k] = 0.f;
#pragma unroll
    for (int p = 0; p < 8; ++p) {
        const unsigned* w2row = W2p + (wq * 8 + p) * 16;  // wave-uniform
#pragma unroll
        for (int k = 0; k < 2 + CCH; ++k) o[k] = dot2f(hp[p], w2row[k], o[k]);
    }

#pragma unroll
    for (int k = 0; k < 2 + CCH; ++k) part[wq][lane][k] = o[k];
    __syncthreads();

    // epilogue duties split by wave
    if (wq == 0) {
        float s0 = part[0][lane][0] + part[1][lane][0] + part[2][lane][0] + part[3][lane][0] + b2[0];
        float s1 = part[0][lane][1] + part[1][lane][1] + part[2][lane][1] + part[3][lane][1] + b2[1];
        float npx = px + s0 * DT;
        if (npx >= (float)GRIDN) npx -= (float)GRIDN;
        if (npx < 0.f) npx += (float)GRIDN;
        float npy = py + s1 * DT;
        if (npy >= (float)GRIDN) npy -= (float)GRIDN;
        if (npy < 0.f) npy += (float)GRIDN;
        out_pos[i] = npx;
        out_pos[i + NAGENTS] = npy;
        out_vel[i] = s0;
        out_vel[i + NAGENTS] = s1;
    } else if (wq == 1) {
        float d0 = part[0][lane][2] + part[1][lane][2] + part[2][lane][2] + part[3][lane][2] + b2[2];
        float d1 = part[0][lane][3] + part[1][lane][3] + part[2][lane][3] + part[3][lane][3] + b2[3];
        float d2 = part[0][lane][4] + part[1][lane][4] + part[2][lane][4] + part[3][lane][4] + b2[4];
        float d3 = part[0][lane][5] + part[1][lane][5] + part[2][lane][5] + part[3][lane][5] + b2[5];
        *(float4*)(dp + (size_t)i * CCH) = make_float4(d0, d1, d2, d3);
    } else if (wq == 2) {
        float d4 = part[0][lane][6] + part[1][lane][6] + part[2][lane][6] + part[3][lane][6] + b2[6];
        float d5 = part[0][lane][7] + part[1][lane][7] + part[2][lane][7] + part[3][lane][7] + b2[7];
        float d6 = part[0][lane][8] + part[1][lane][8] + part[2][lane][8] + part[3][lane][8] + b2[8];
        float d7 = part[0][lane][9] + part[1][lane][9] + part[2][lane][9] + part[3][lane][9] + b2[9];
        *(float4*)(dp + (size_t)i * CCH + 4) = make_float4(d4, d5, d6, d7);
    } else {
        int wx = (int)rintf(px) & (GRIDN - 1);
        int wy = (int)rintf(py) & (GRIDN - 1);
        atomicMax(&winner[(wx << 10) + wy], i);
    }
}

__global__ void __launch_bounds__(256) k_update(const float* __restrict__ lat,
                                                const int* __restrict__ winner,
                                                const float* __restrict__ dp,
                                                float* __restrict__ out_lat) {
    int idx = blockIdx.x * blockDim.x + threadIdx.x;  // cell index
    int w = winner[idx];
    float d[CCH];
    if (w >= 0) {
        const float4* dpp = (const float4*)(dp + (size_t)w * CCH);
        float4 a = dpp[0], b = dpp[1];
        d[0] = a.x; d[1] = a.y; d[2] = a.z; d[3] = a.w;
        d[4] = b.x; d[5] = b.y; d[6] = b.z; d[7] = b.w;
    }
#pragma unroll
    for (int c = 0; c < CCH; ++c) {
        size_t off = (size_t)c * GRIDN * GRIDN + idx;
        float v = lat[off];
        if (w >= 0) v = fmaxf(v + DT * d[c], 0.f);
        out_lat[off] = v * DECAYF;
    }
}

extern "C" void kernel_launch(void* const* d_in, const int* in_sizes, int n_in,
                              void* d_out, int out_size, void* d_ws, size_t ws_size,
                              hipStream_t stream) {
    const float* pos = (const float*)d_in[0];
    const float* vel = (const float*)d_in[1];
    const float* lat = (const float*)d_in[2];
    const float* W1  = (const float*)d_in[3];
    const float* b1  = (const float*)d_in[4];
    const float* W2  = (const float*)d_in[5];
    const float* b2  = (const float*)d_in[6];

    float* out      = (float*)d_out;
    float* out_pos  = out;                 // (2, N)
    float* out_vel  = out + 2 * NAGENTS;   // (2, N)
    float* out_lat  = out + 4 * NAGENTS;   // (C, G, G)

    char* ws = (char*)d_ws;
    int*       winner = (int*)ws;                       // 4 MB
    float*     dp     = (float*)(ws + (4 << 20));       // 8 MB
    _Float16*  BT     = (_Float16*)(ws + (12 << 20));   // 16 MB
    unsigned*  W1p    = (unsigned*)(ws + (28 << 20));   // 3 KB
    unsigned*  W2p    = (unsigned*)(ws + (28 << 20) + 4096);  // 2 KB

    const int ncell = GRIDN * GRIDN;

    k_boxT<<<ncell / 256, 256, 0, stream>>>(lat, BT, winner, W1, W2, W1p, W2p);
    k_agent<<<NAGENTS / 64, 256, 0, stream>>>(pos, vel, BT, W1p, b1, W2p, b2,
                                              out_pos, out_vel, dp, winner);
    k_update<<<ncell / 256, 256, 0, stream>>>(lat, winner, dp, out_lat);
}